// Round 3
// baseline (400.238 us; speedup 1.0000x reference)
//
#include <hip/hip_runtime.h>
#include <hip/hip_bf16.h>
#include <hip/hip_cooperative_groups.h>
#include <stdint.h>

namespace cg = cooperative_groups;

// Problem constants (fixed by the reference)
#define M_ROWS 4096   // B
#define N_COLS 8192   // N
#define KDIM   512    // D

// GEMM: 256x256 tile, 8 waves (2M x 4N), BK=32 K-tiles, 4-deep LDS ring
#define BM 256
#define BN 256
#define BKT 32
#define NKT 16        // K-tiles per output tile (512/32)

typedef __attribute__((ext_vector_type(8))) __bf16 bf16x8;
typedef __attribute__((ext_vector_type(4))) float  f32x4;
typedef __attribute__((ext_vector_type(4))) int    i32x4;

// compiler-only fence + hw barrier (raw: no implicit vmcnt(0) drain)
#define BAR() do { asm volatile("" ::: "memory"); \
                   __builtin_amdgcn_s_barrier();  \
                   asm volatile("" ::: "memory"); } while (0)

// ---------- fp32 -> bf16 (RNE) ----------
__device__ __forceinline__ unsigned short f2bf(float f) {
  union { float f; uint32_t u; } v; v.f = f;
  uint32_t u = v.u;
  u += 0x7fffu + ((u >> 16) & 1u);
  return (unsigned short)(u >> 16);
}

// ---------- LDS swizzle (as R2: 2-lane/bank frag reads) ----------
__device__ __forceinline__ int swz_x(int r) { return (r & 3) ^ ((r >> 2) & 3); }

__device__ __forceinline__ bf16x8 lds_frag(const unsigned short* chunk, int r, int lk) {
  int g = lk ^ swz_x(r);
  return *reinterpret_cast<const bf16x8*>(chunk + r * 32 + g * 8);
}

// stage one 16KB chunk (256 rows x 32 k). LDS dest linear; swizzle applied by
// permuting the per-lane GLOBAL source granule (rule 21).
__device__ __forceinline__ void stage_chunk(const unsigned short* __restrict__ srcBase,
                                            int tt, unsigned short* chunk,
                                            int w, int l) {
  #pragma unroll
  for (int jj = 0; jj < 2; ++jj) {
    int r = jj * 128 + w * 16 + (l >> 2);
    int g = (l & 3) ^ swz_x(r);
    const unsigned short* src = srcBase + (size_t)r * KDIM + tt * BKT + g * 8;
    __builtin_amdgcn_global_load_lds(
        (const __attribute__((address_space(1))) void*)src,
        (__attribute__((address_space(3))) void*)(chunk + jj * 4096 + w * 512),
        16, 0, 0);
  }
}

// one K-tile. SCAN: 4 nontemporal int4 one-hot loads issued in phase0,
// examined after phase1's MFMAs (compiler inserts the value-wait; staging
// correctness is still governed by the manual counted vmcnt).
template<bool STAGE, bool SCAN, int VM>
__device__ __forceinline__ void ktile(int t, unsigned short (*lds)[2][BM * BKT],
                                      const unsigned short* __restrict__ Abase,
                                      const unsigned short* __restrict__ Sbase,
                                      const i32x4* __restrict__ scanBase,
                                      int* pos_lds,
                                      f32x4 (&acc)[8][4],
                                      int wr, int wc, int lr, int lk,
                                      int w, int l, int tid) {
  const unsigned short* cA = lds[t & 3][0];
  const unsigned short* cB = lds[t & 3][1];
  bf16x8 bfr[4], afr[4];
  i32x4 sv[4];
  // phase 0: B-frags (held both phases) + A-frags m=0..3; stage A(t+3); scan row t
  #pragma unroll
  for (int n = 0; n < 4; ++n) bfr[n] = lds_frag(cB, wc * 64 + n * 16 + lr, lk);
  #pragma unroll
  for (int m = 0; m < 4; ++m) afr[m] = lds_frag(cA, wr * 128 + m * 16 + lr, lk);
  if (STAGE) stage_chunk(Abase, t + 3, lds[(t + 3) & 3][0], w, l);
  if (SCAN) {
    #pragma unroll
    for (int i = 0; i < 4; ++i)
      sv[i] = __builtin_nontemporal_load(&scanBase[t * 2048 + i * 512 + tid]);
  }
  BAR();
  __builtin_amdgcn_s_setprio(1);
  #pragma unroll
  for (int m = 0; m < 4; ++m)
    #pragma unroll
    for (int n = 0; n < 4; ++n)
      acc[m][n] = __builtin_amdgcn_mfma_f32_16x16x32_bf16(afr[m], bfr[n],
                                                          acc[m][n], 0, 0, 0);
  __builtin_amdgcn_s_setprio(0);
  BAR();
  // phase 1: A-frags m=4..7; stage B(t+3)
  #pragma unroll
  for (int m = 0; m < 4; ++m) afr[m] = lds_frag(cA, wr * 128 + (m + 4) * 16 + lr, lk);
  if (STAGE) stage_chunk(Sbase, t + 3, lds[(t + 3) & 3][1], w, l);
  BAR();
  __builtin_amdgcn_s_setprio(1);
  #pragma unroll
  for (int m = 0; m < 4; ++m)
    #pragma unroll
    for (int n = 0; n < 4; ++n)
      acc[m + 4][n] = __builtin_amdgcn_mfma_f32_16x16x32_bf16(afr[m], bfr[n],
                                                              acc[m + 4][n], 0, 0, 0);
  __builtin_amdgcn_s_setprio(0);
  if (SCAN) {
    // K-tile t scans exactly one-hot row t of this block's 16 rows:
    // int4 index i*512+tid in [0,2048) -> col = 4*that + subword.
    #pragma unroll
    for (int i = 0; i < 4; ++i) {
      i32x4 v = sv[i];
      if (v[0] | v[1] | v[2] | v[3]) {
        int col = (i * 512 + tid) * 4 + (v[0] ? 0 : (v[1] ? 1 : (v[2] ? 2 : 3)));
        pos_lds[t] = col;   // exactly one nonzero per row -> single writer
      }
    }
  }
  if (VM == 16)      asm volatile("s_waitcnt vmcnt(16)" ::: "memory");
  else if (VM == 12) asm volatile("s_waitcnt vmcnt(12)" ::: "memory");
  else if (VM == 8)  asm volatile("s_waitcnt vmcnt(8)" ::: "memory");
  else if (VM == 4)  asm volatile("s_waitcnt vmcnt(4)" ::: "memory");
  else if (VM == 0)  asm volatile("s_waitcnt vmcnt(0)" ::: "memory");
  BAR();
}

// one full output tile's K-loop (prologue + 16 K-tiles)
template<bool SCAN>
__device__ __forceinline__ void gemm_tile(unsigned short (*lds)[2][BM * BKT],
                                          const unsigned short* __restrict__ Abase,
                                          const unsigned short* __restrict__ Sbase,
                                          const i32x4* __restrict__ scanBase,
                                          int* pos_lds,
                                          f32x4 (&acc)[8][4],
                                          int wr, int wc, int lr, int lk,
                                          int w, int l, int tid) {
  #pragma unroll
  for (int tt = 0; tt < 3; ++tt) {
    stage_chunk(Abase, tt, lds[tt][0], w, l);
    stage_chunk(Sbase, tt, lds[tt][1], w, l);
  }
  asm volatile("s_waitcnt vmcnt(8)" ::: "memory");  // tile 0 landed
  BAR();
  #pragma unroll 1
  for (int kt = 0; kt < NKT - 3; ++kt)
    ktile<true, SCAN, SCAN ? 16 : 8>(kt, lds, Abase, Sbase, scanBase, pos_lds,
                                     acc, wr, wc, lr, lk, w, l, tid);
  ktile<false, SCAN, SCAN ? 12 : 4>(NKT - 3, lds, Abase, Sbase, scanBase, pos_lds,
                                    acc, wr, wc, lr, lk, w, l, tid);
  ktile<false, SCAN, SCAN ? 8 : 0>(NKT - 2, lds, Abase, Sbase, scanBase, pos_lds,
                                   acc, wr, wc, lr, lk, w, l, tid);
  ktile<false, SCAN, -1>(NKT - 1, lds, Abase, Sbase, scanBase, pos_lds,
                         acc, wr, wc, lr, lk, w, l, tid);
}

// hinge epilogue: one scalar per (block, tile) in fixed order.
// C/D layout: col = lane&15, row = (lane>>4)*4 + reg (verified m89).
__device__ __forceinline__ void epilogue(f32x4 (&acc)[8][4], int rowBase,
                                         const float* __restrict__ s_pos,
                                         float* wred, double* dst,
                                         int tid, int w, int lane,
                                         int wr, int lk) {
  float lsum = 0.f;
  const int rl = lk * 4;
  #pragma unroll
  for (int m = 0; m < 8; ++m) {
    float sp[4];
    #pragma unroll
    for (int r = 0; r < 4; ++r)
      sp[r] = s_pos[rowBase + wr * 128 + m * 16 + rl + r];
    #pragma unroll
    for (int n = 0; n < 4; ++n)
      #pragma unroll
      for (int r = 0; r < 4; ++r)
        lsum += fmaxf(acc[m][n][r] - sp[r] + 1.0f, 0.f);
  }
  #pragma unroll
  for (int off = 32; off > 0; off >>= 1) lsum += __shfl_down(lsum, off, 64);
  if (lane == 0) wred[w] = lsum;
  __syncthreads();
  if (tid == 0) {
    float s = 0.f;
    #pragma unroll
    for (int i = 0; i < 8; ++i) s += wred[i];
    *dst = (double)s;
  }
  __syncthreads();   // protect wred reuse
}

// ---------- the single fused cooperative kernel ----------
__global__ __launch_bounds__(512, 2) void fused_kernel(
    const float* __restrict__ A, const float* __restrict__ S,
    const int* __restrict__ onehot,
    unsigned short* __restrict__ Abf, unsigned short* __restrict__ Sbf,
    float* __restrict__ s_pos, double* __restrict__ partial,
    float* __restrict__ out) {
  __shared__ alignas(16) unsigned short lds[4][2][BM * BKT];  // 128 KB ring
  __shared__ int pos_lds[16];
  __shared__ float wred[8];
  __shared__ double sdd[8];

  const int tid  = threadIdx.x;
  const int blk  = blockIdx.x;          // 256 blocks, 1/CU (cooperative)
  const int w    = tid >> 6;
  const int lane = tid & 63;
  const int wr   = w >> 2, wc = w & 3;
  const int lr   = lane & 15, lk = lane >> 4;

  // ---- phase A: fp32 -> bf16 of A (524288 f4) then S (1048576 f4) ----
  #pragma unroll
  for (int k2 = 0; k2 < 12; ++k2) {
    int idx = k2 * 131072 + blk * 512 + tid;
    float4 v; ushort4 o;
    if (idx < 524288) {
      v = reinterpret_cast<const float4*>(A)[idx];
      o.x = f2bf(v.x); o.y = f2bf(v.y); o.z = f2bf(v.z); o.w = f2bf(v.w);
      reinterpret_cast<ushort4*>(Abf)[idx] = o;
    } else {
      int q = idx - 524288;
      v = reinterpret_cast<const float4*>(S)[q];
      o.x = f2bf(v.x); o.y = f2bf(v.y); o.z = f2bf(v.z); o.w = f2bf(v.w);
      reinterpret_cast<ushort4*>(Sbf)[q] = o;
    }
  }
  if (tid < 16) pos_lds[tid] = 0;
  __threadfence();
  cg::this_grid().sync();
  __threadfence();   // reader-side: invalidate stale L2 (cross-XCD)

  const int rp = blk & 15;
  const int rowBase = rp * BM;
  const unsigned short* Abase = Abf + (size_t)rowBase * KDIM;
  const i32x4* scanBase = reinterpret_cast<const i32x4*>(onehot + (size_t)blk * 16 * N_COLS);

  f32x4 acc[8][4];
  #pragma unroll
  for (int m = 0; m < 8; ++m)
    #pragma unroll
    for (int n = 0; n < 4; ++n)
      acc[m][n] = (f32x4){0.f, 0.f, 0.f, 0.f};

  // ---- tile 1 (cp = blk>>4) with the one-hot scan overlapped ----
  {
    const unsigned short* Sbase = Sbf + (size_t)(blk >> 4) * BN * KDIM;
    gemm_tile<true>(lds, Abase, Sbase, scanBase, pos_lds, acc,
                    wr, wc, lr, lk, w, lane, tid);
  }

  // ---- fp32 pos-dots for this block's 16 scanned rows ----
  __syncthreads();   // pos_lds visible
  #pragma unroll
  for (int rr = 0; rr < 2; ++rr) {
    int r = w * 2 + rr;
    int b = blk * 16 + r;
    int j = pos_lds[r];
    const float4* a4 = reinterpret_cast<const float4*>(A + (size_t)b * KDIM);
    const float4* s4 = reinterpret_cast<const float4*>(S + (size_t)j * KDIM);
    float4 x0 = a4[lane * 2], x1 = a4[lane * 2 + 1];
    float4 y0 = s4[lane * 2], y1 = s4[lane * 2 + 1];
    float sum = x0.x * y0.x + x0.y * y0.y + x0.z * y0.z + x0.w * y0.w
              + x1.x * y1.x + x1.y * y1.y + x1.z * y1.z + x1.w * y1.w;
    #pragma unroll
    for (int off = 32; off > 0; off >>= 1) sum += __shfl_down(sum, off, 64);
    if (lane == 0) s_pos[b] = sum;
  }
  __threadfence();
  cg::this_grid().sync();
  __threadfence();   // reader-side invalidate before consuming s_pos

  // ---- tile 1 epilogue ----
  epilogue(acc, rowBase, s_pos, wred, &partial[blk], tid, w, lane, wr, lk);

  #pragma unroll
  for (int m = 0; m < 8; ++m)
    #pragma unroll
    for (int n = 0; n < 4; ++n)
      acc[m][n] = (f32x4){0.f, 0.f, 0.f, 0.f};

  // ---- tile 2 (cp = 16 + blk>>4), no scan ----
  {
    const unsigned short* Sbase = Sbf + (size_t)(16 + (blk >> 4)) * BN * KDIM;
    gemm_tile<false>(lds, Abase, Sbase, scanBase, pos_lds, acc,
                     wr, wc, lr, lk, w, lane, tid);
  }
  epilogue(acc, rowBase, s_pos, wred, &partial[blk + 256], tid, w, lane, wr, lk);

  __threadfence();
  cg::this_grid().sync();
  __threadfence();

  // ---- final deterministic reduction (block 0) ----
  if (blk == 0) {
    double s = partial[tid];   // exactly 512 partials
    #pragma unroll
    for (int off = 32; off > 0; off >>= 1) s += __shfl_down(s, off, 64);
    if (lane == 0) sdd[w] = s;
    __syncthreads();
    if (tid == 0) {
      double tot = 0.0;
      #pragma unroll
      for (int i = 0; i < 8; ++i) tot += sdd[i];
      // positive entry contributes exactly 1 per row -> subtract B
      out[0] = (float)((tot - (double)M_ROWS) /
                       ((double)M_ROWS * (double)(N_COLS - 1)));
    }
  }
}

extern "C" void kernel_launch(void* const* d_in, const int* in_sizes, int n_in,
                              void* d_out, int out_size, void* d_ws, size_t ws_size,
                              hipStream_t stream) {
  const float* A  = (const float*)d_in[0];   // anchor [4096,512] f32
  const float* S  = (const float*)d_in[1];   // sample [8192,512] f32
  const int*   oh = (const int*)d_in[2];     // one-hot [4096,8192] int
  float* out = (float*)d_out;

  // workspace layout (~12.1 MB): partials | s_pos | A_bf16 | S_bf16
  char* ws = (char*)d_ws;
  double* partial = (double*)ws;                           // 512 * 8B
  float* s_pos    = (float*)(ws + 16384);                  // 4096 * 4B
  unsigned short* Abf = (unsigned short*)(ws + 32768);     // 4 MB
  unsigned short* Sbf = Abf + (size_t)M_ROWS * KDIM;       // 8 MB

  void* args[] = {(void*)&A, (void*)&S, (void*)&oh, (void*)&Abf, (void*)&Sbf,
                  (void*)&s_pos, (void*)&partial, (void*)&out};
  hipLaunchCooperativeKernel((void*)fused_kernel, dim3(256), dim3(512),
                             args, 0, stream);
}

// Round 4
// 103.076 us; speedup vs baseline: 3.8830x; 3.8830x over previous
//
#include <hip/hip_runtime.h>
#include <hip/hip_bf16.h>
#include <stdint.h>

// Problem constants (fixed by the reference)
#define M_ROWS 4096   // B
#define N_COLS 8192   // N
#define KDIM   512    // D

// GEMM: 256x256 tile, 8 waves (2M x 4N), BK=32 K-tiles, 4-deep LDS ring
#define BM 256
#define BN 256
#define BKT 32
#define NKT 16        // 512 / 32

typedef __attribute__((ext_vector_type(8))) __bf16 bf16x8;
typedef __attribute__((ext_vector_type(4))) float  f32x4;
typedef __attribute__((ext_vector_type(4))) int    i32x4;

// compiler-only fence + hw barrier (raw: no implicit vmcnt(0) drain)
#define BAR() do { asm volatile("" ::: "memory"); \
                   __builtin_amdgcn_s_barrier();  \
                   asm volatile("" ::: "memory"); } while (0)

// ---------- fp32 -> bf16 (RNE) ----------
__device__ __forceinline__ unsigned short f2bf(float f) {
  union { float f; uint32_t u; } v; v.f = f;
  uint32_t u = v.u;
  u += 0x7fffu + ((u >> 16) & 1u);
  return (unsigned short)(u >> 16);
}

// ---------- kernel 1: fp32 -> bf16 conversion only ----------
__global__ __launch_bounds__(256) void cvt_kernel(const float* __restrict__ A,
                                                  const float* __restrict__ S,
                                                  unsigned short* __restrict__ Abf,
                                                  unsigned short* __restrict__ Sbf) {
  // A: 524288 float4, S: 1048576 float4 -> 1572864 total; 1536x256 thr x 4 it
  int g = blockIdx.x * 256 + threadIdx.x;
  #pragma unroll
  for (int it = 0; it < 4; ++it) {
    int idx = g + it * 393216;
    float4 v; ushort4 o;
    if (idx < 524288) {
      v = reinterpret_cast<const float4*>(A)[idx];
      o.x = f2bf(v.x); o.y = f2bf(v.y); o.z = f2bf(v.z); o.w = f2bf(v.w);
      reinterpret_cast<ushort4*>(Abf)[idx] = o;
    } else {
      int q = idx - 524288;
      v = reinterpret_cast<const float4*>(S)[q];
      o.x = f2bf(v.x); o.y = f2bf(v.y); o.z = f2bf(v.z); o.w = f2bf(v.w);
      reinterpret_cast<ushort4*>(Sbf)[q] = o;
    }
  }
}

// ---------- GEMM helpers (identical to the verified R2 core) ----------
__device__ __forceinline__ int swz_x(int r) { return (r & 3) ^ ((r >> 2) & 3); }

__device__ __forceinline__ bf16x8 lds_frag(const unsigned short* chunk, int r, int lk) {
  int g = lk ^ swz_x(r);
  return *reinterpret_cast<const bf16x8*>(chunk + r * 32 + g * 8);
}

__device__ __forceinline__ void stage_chunk(const unsigned short* __restrict__ srcBase,
                                            int tt, unsigned short* chunk,
                                            int w, int l) {
  #pragma unroll
  for (int jj = 0; jj < 2; ++jj) {
    int r = jj * 128 + w * 16 + (l >> 2);
    int g = (l & 3) ^ swz_x(r);
    const unsigned short* src = srcBase + (size_t)r * KDIM + tt * BKT + g * 8;
    __builtin_amdgcn_global_load_lds(
        (const __attribute__((address_space(1))) void*)src,
        (__attribute__((address_space(3))) void*)(chunk + jj * 4096 + w * 512),
        16, 0, 0);
  }
}

// consume one scan pair loaded at tile TSRC (registers -> LDS pos slot).
// ds_write affects lgkmcnt only, so hand-counted vmcnt staging stays exact.
template<int TSRC>
__device__ __forceinline__ void consume_scan(i32x4 (&sv)[2][2], int* pos_lds, int tid) {
  #pragma unroll
  for (int j = 0; j < 2; ++j) {
    i32x4 v = sv[TSRC & 1][j];
    if (v[0] | v[1] | v[2] | v[3]) {
      int li4 = (TSRC * 512 + tid) * 2 + j;
      int sub = v[0] ? 0 : (v[1] ? 1 : (v[2] ? 2 : 3));
      pos_lds[li4 >> 11] = ((li4 & 2047) << 2) + sub;
    }
  }
}

// One K-tile, R2 structure + scan injection (load at T, consume at T+2).
// vmcnt ledger (2 ops per stage, 2 per scan): steady in-flight at tile end =
// [B(t+1),A(t+2),s(t-1),B(t+2),A(t+3),s(t),B(t+3)] = 14; staging(t+1) done
// after vmcnt(12). t=0: 10 (no s(-1)). t=13: 8. t=14: 4. t=15: none.
template<int T>
__device__ __forceinline__ void do_tile(unsigned short (*lds)[2][BM * BKT],
                                        const unsigned short* __restrict__ Abase,
                                        const unsigned short* __restrict__ Sbase,
                                        const i32x4* __restrict__ scanB,
                                        int* pos_lds,
                                        i32x4 (&sv)[2][2], f32x4 (&acc)[8][4],
                                        int wr, int wc, int lr, int lk,
                                        int w, int lane, int tid) {
  constexpr bool STAGE = (T <= NKT - 4);     // stage tiles T+3 <= 15
  const unsigned short* cA = lds[T & 3][0];
  const unsigned short* cB = lds[T & 3][1];

  if constexpr (T >= 2) consume_scan<T - 2>(sv, pos_lds, tid);

  bf16x8 bfr[4], afr[4];
  #pragma unroll
  for (int n = 0; n < 4; ++n) bfr[n] = lds_frag(cB, wc * 64 + n * 16 + lr, lk);
  #pragma unroll
  for (int m = 0; m < 4; ++m) afr[m] = lds_frag(cA, wr * 128 + m * 16 + lr, lk);
  if constexpr (STAGE) stage_chunk(Abase, T + 3, lds[(T + 3) & 3][0], w, lane);
  #pragma unroll
  for (int j = 0; j < 2; ++j)
    sv[T & 1][j] = __builtin_nontemporal_load(scanB + (size_t)((T * 512 + tid) * 2 + j));
  BAR();
  __builtin_amdgcn_s_setprio(1);
  #pragma unroll
  for (int m = 0; m < 4; ++m)
    #pragma unroll
    for (int n = 0; n < 4; ++n)
      acc[m][n] = __builtin_amdgcn_mfma_f32_16x16x32_bf16(afr[m], bfr[n],
                                                          acc[m][n], 0, 0, 0);
  __builtin_amdgcn_s_setprio(0);
  BAR();
  #pragma unroll
  for (int m = 0; m < 4; ++m) afr[m] = lds_frag(cA, wr * 128 + (m + 4) * 16 + lr, lk);
  if constexpr (STAGE) stage_chunk(Sbase, T + 3, lds[(T + 3) & 3][1], w, lane);
  BAR();
  __builtin_amdgcn_s_setprio(1);
  #pragma unroll
  for (int m = 0; m < 4; ++m)
    #pragma unroll
    for (int n = 0; n < 4; ++n)
      acc[m + 4][n] = __builtin_amdgcn_mfma_f32_16x16x32_bf16(afr[m], bfr[n],
                                                              acc[m + 4][n], 0, 0, 0);
  __builtin_amdgcn_s_setprio(0);
  if constexpr (T == 0)                 asm volatile("s_waitcnt vmcnt(10)" ::: "memory");
  else if constexpr (T >= 1 && T <= 12) asm volatile("s_waitcnt vmcnt(12)" ::: "memory");
  else if constexpr (T == 13)           asm volatile("s_waitcnt vmcnt(8)"  ::: "memory");
  else if constexpr (T == 14)           asm volatile("s_waitcnt vmcnt(4)"  ::: "memory");
  BAR();
}

// ---------- kernel 2: GEMM + overlapped one-hot scan + row sum/min ----------
__global__ __launch_bounds__(512, 2) void gemm_scan_kernel(
    const unsigned short* __restrict__ Abf,
    const unsigned short* __restrict__ Sbf,
    const int* __restrict__ onehot,
    int* __restrict__ pos_idx,
    float* __restrict__ rsum, float* __restrict__ rmin) {
  __shared__ alignas(16) unsigned short lds[4][2][BM * BKT];  // 128 KB ring
  __shared__ int pos_lds[8];

  const int tid  = threadIdx.x;
  const int bx   = blockIdx.x;          // 512 blocks: 16 row-panels x 32 col
  const int w    = tid >> 6;
  const int lane = tid & 63;
  const int wr   = w >> 2, wc = w & 3;
  const int lr   = lane & 15, lk = lane >> 4;
  const int rp   = bx & 15, cp = bx >> 4;
  const int rowBase = rp * BM;

  const unsigned short* Abase = Abf + (size_t)rowBase * KDIM;
  const unsigned short* Sbase = Sbf + (size_t)cp * BN * KDIM;
  const i32x4* scanB = reinterpret_cast<const i32x4*>(onehot + (size_t)bx * 8 * N_COLS);

  f32x4 acc[8][4];
  #pragma unroll
  for (int m = 0; m < 8; ++m)
    #pragma unroll
    for (int n = 0; n < 4; ++n)
      acc[m][n] = (f32x4){0.f, 0.f, 0.f, 0.f};
  i32x4 sv[2][2];

  // prologue: stage tiles 0,1,2 (12 vm ops); vmcnt(8) -> tile 0 landed
  #pragma unroll
  for (int tt = 0; tt < 3; ++tt) {
    stage_chunk(Abase, tt, lds[tt][0], w, lane);
    stage_chunk(Sbase, tt, lds[tt][1], w, lane);
  }
  asm volatile("s_waitcnt vmcnt(8)" ::: "memory");
  BAR();

  do_tile<0>(lds, Abase, Sbase, scanB, pos_lds, sv, acc, wr, wc, lr, lk, w, lane, tid);
  do_tile<1>(lds, Abase, Sbase, scanB, pos_lds, sv, acc, wr, wc, lr, lk, w, lane, tid);
  do_tile<2>(lds, Abase, Sbase, scanB, pos_lds, sv, acc, wr, wc, lr, lk, w, lane, tid);
  do_tile<3>(lds, Abase, Sbase, scanB, pos_lds, sv, acc, wr, wc, lr, lk, w, lane, tid);
  do_tile<4>(lds, Abase, Sbase, scanB, pos_lds, sv, acc, wr, wc, lr, lk, w, lane, tid);
  do_tile<5>(lds, Abase, Sbase, scanB, pos_lds, sv, acc, wr, wc, lr, lk, w, lane, tid);
  do_tile<6>(lds, Abase, Sbase, scanB, pos_lds, sv, acc, wr, wc, lr, lk, w, lane, tid);
  do_tile<7>(lds, Abase, Sbase, scanB, pos_lds, sv, acc, wr, wc, lr, lk, w, lane, tid);
  do_tile<8>(lds, Abase, Sbase, scanB, pos_lds, sv, acc, wr, wc, lr, lk, w, lane, tid);
  do_tile<9>(lds, Abase, Sbase, scanB, pos_lds, sv, acc, wr, wc, lr, lk, w, lane, tid);
  do_tile<10>(lds, Abase, Sbase, scanB, pos_lds, sv, acc, wr, wc, lr, lk, w, lane, tid);
  do_tile<11>(lds, Abase, Sbase, scanB, pos_lds, sv, acc, wr, wc, lr, lk, w, lane, tid);
  do_tile<12>(lds, Abase, Sbase, scanB, pos_lds, sv, acc, wr, wc, lr, lk, w, lane, tid);
  do_tile<13>(lds, Abase, Sbase, scanB, pos_lds, sv, acc, wr, wc, lr, lk, w, lane, tid);
  do_tile<14>(lds, Abase, Sbase, scanB, pos_lds, sv, acc, wr, wc, lr, lk, w, lane, tid);
  do_tile<15>(lds, Abase, Sbase, scanB, pos_lds, sv, acc, wr, wc, lr, lk, w, lane, tid);

  // drain remaining scan pairs (tiles 14, 15)
  consume_scan<14>(sv, pos_lds, tid);
  consume_scan<15>(sv, pos_lds, tid);
  __syncthreads();

  // ---- epilogue: per-row (sum, min) over this block's 256 cols ----
  // C/D layout: col = wc*64 + n*16 + (lane&15); row = wr*128 + m*16 + lk*4 + r.
  // Reduce over n in-reg, then 2-step shfl_xor(4,8) -> per-class (lane&3)
  // partials over the 16-col group; combine the 4 waves (wc) via LDS.
  float* eps = (float*)&lds[0][0][0];     // [256 rows][4 cls][4 wc] floats
  float* epm = eps + 4096;
  #pragma unroll
  for (int m = 0; m < 8; ++m)
    #pragma unroll
    for (int r = 0; r < 4; ++r) {
      float s_ = (acc[m][0][r] + acc[m][1][r]) + (acc[m][2][r] + acc[m][3][r]);
      float n_ = fminf(fminf(acc[m][0][r], acc[m][1][r]),
                       fminf(acc[m][2][r], acc[m][3][r]));
      s_ += __shfl_xor(s_, 4, 64);
      n_ = fminf(n_, __shfl_xor(n_, 4, 64));
      s_ += __shfl_xor(s_, 8, 64);
      n_ = fminf(n_, __shfl_xor(n_, 8, 64));
      if ((lane & 12) == 0) {
        int row = wr * 128 + m * 16 + lk * 4 + r;
        int cls = lane & 3;
        eps[(row * 4 + cls) * 4 + wc] = s_;
        epm[(row * 4 + cls) * 4 + wc] = n_;
      }
    }
  __syncthreads();
  #pragma unroll
  for (int item = tid; item < 1024; item += 512) {
    int row = item >> 2, cls = item & 3;
    float s0 = (eps[item * 4 + 0] + eps[item * 4 + 1]) +
               (eps[item * 4 + 2] + eps[item * 4 + 3]);
    float m0 = fminf(fminf(epm[item * 4 + 0], epm[item * 4 + 1]),
                     fminf(epm[item * 4 + 2], epm[item * 4 + 3]));
    size_t gi = (size_t)(rowBase + row) * 128 + cp * 4 + cls;
    rsum[gi] = s0;
    rmin[gi] = m0;
  }
  if (tid < 8) pos_idx[bx * 8 + tid] = pos_lds[tid];
}

// ---------- kernel 3: per-row loss via the no-clip identity ----------
// rowLoss = (R - p) - (N-1)(p-1) when min_n s >= p-1 (exact; pos term excluded
// up to the bf16-vs-fp32 difference of one dot / (N-1) ~ 4e-8). Guarded exact
// fp32 slow path otherwise.
__global__ __launch_bounds__(256) void fin1_kernel(
    const float* __restrict__ A, const float* __restrict__ Sm,
    const int* __restrict__ pos_idx,
    const float* __restrict__ rsum, const float* __restrict__ rmin,
    float* __restrict__ rowLoss) {
  const int w = threadIdx.x >> 6, lane = threadIdx.x & 63;
  #pragma unroll
  for (int i = 0; i < 2; ++i) {
    int row = blockIdx.x * 8 + w * 2 + i;
    int j = pos_idx[row];
    const float4* a4 = reinterpret_cast<const float4*>(A + (size_t)row * KDIM);
    const float4* s4 = reinterpret_cast<const float4*>(Sm + (size_t)j * KDIM);
    float4 x0 = a4[lane * 2], x1 = a4[lane * 2 + 1];
    float4 y0 = s4[lane * 2], y1 = s4[lane * 2 + 1];
    float dp = x0.x * y0.x + x0.y * y0.y + x0.z * y0.z + x0.w * y0.w
             + x1.x * y1.x + x1.y * y1.y + x1.z * y1.z + x1.w * y1.w;
    float rs = rsum[(size_t)row * 128 + lane] + rsum[(size_t)row * 128 + 64 + lane];
    float rm = fminf(rmin[(size_t)row * 128 + lane],
                     rmin[(size_t)row * 128 + 64 + lane]);
    #pragma unroll
    for (int off = 32; off > 0; off >>= 1) {
      dp += __shfl_down(dp, off, 64);
      rs += __shfl_down(rs, off, 64);
      rm = fminf(rm, __shfl_down(rm, off, 64));
    }
    float p  = __shfl(dp, 0, 64);
    float R  = __shfl(rs, 0, 64);
    float mn = __shfl(rm, 0, 64);
    float loss;
    if (mn >= p - 1.0f) {
      loss = (R - p) - (float)(N_COLS - 1) * (p - 1.0f);
    } else {
      // exact fp32 recompute of this row (not expected to trigger)
      float accv = 0.f;
      const float* arow = A + (size_t)row * KDIM;
      for (int n = lane; n < N_COLS; n += 64) {
        const float* srow = Sm + (size_t)n * KDIM;
        float d = 0.f;
        for (int k = 0; k < KDIM; ++k) d += arow[k] * srow[k];
        float h = fmaxf(d - p + 1.0f, 0.0f);
        accv += (n == j) ? 0.f : h;
      }
      #pragma unroll
      for (int off = 32; off > 0; off >>= 1) accv += __shfl_down(accv, off, 64);
      loss = __shfl(accv, 0, 64);
    }
    if (lane == 0) rowLoss[row] = loss;
  }
}

// ---------- kernel 4: deterministic final scalar ----------
__global__ __launch_bounds__(256) void fin2_kernel(const float* __restrict__ rowLoss,
                                                   float* __restrict__ out) {
  __shared__ double sd[256];
  double s = 0.0;
  for (int i = threadIdx.x; i < M_ROWS; i += 256) s += (double)rowLoss[i];
  sd[threadIdx.x] = s;
  __syncthreads();
  for (int st = 128; st > 0; st >>= 1) {
    if (threadIdx.x < st) sd[threadIdx.x] += sd[threadIdx.x + st];
    __syncthreads();
  }
  if (threadIdx.x == 0)
    *out = (float)(sd[0] / ((double)M_ROWS * (double)(N_COLS - 1)));
}

extern "C" void kernel_launch(void* const* d_in, const int* in_sizes, int n_in,
                              void* d_out, int out_size, void* d_ws, size_t ws_size,
                              hipStream_t stream) {
  const float* A  = (const float*)d_in[0];   // anchor [4096,512] f32
  const float* S  = (const float*)d_in[1];   // sample [8192,512] f32
  const int*   oh = (const int*)d_in[2];     // one-hot [4096,8192] int
  float* out = (float*)d_out;

  // workspace (~13.1 MB): pos | rsum | rmin | rowLoss | Abf | Sbf
  char* ws = (char*)d_ws;
  int*   pos_idx  = (int*)ws;                               // 16 KB
  float* rsum     = (float*)(ws + 16384);                   // 4096*128*4 = 2 MB
  float* rmin     = (float*)(ws + 16384 + 2097152);         // 2 MB
  float* rowLoss  = (float*)(ws + 16384 + 4194304);         // 16 KB
  unsigned short* Abf = (unsigned short*)(ws + 16384 + 4194304 + 16384);  // 4 MB
  unsigned short* Sbf = Abf + (size_t)M_ROWS * KDIM;        // 8 MB

  cvt_kernel<<<1536, 256, 0, stream>>>(A, S, Abf, Sbf);
  gemm_scan_kernel<<<512, 512, 0, stream>>>(Abf, Sbf, oh, pos_idx, rsum, rmin);
  fin1_kernel<<<512, 256, 0, stream>>>(A, S, pos_idx, rsum, rmin, rowLoss);
  fin2_kernel<<<1, 256, 0, stream>>>(rowLoss, out);
}